// Round 9
// baseline (29026.807 us; speedup 1.0000x reference)
//
#include <hip/hip_runtime.h>

using half8 = __attribute__((ext_vector_type(8))) _Float16;
using f32x4 = __attribute__((ext_vector_type(4))) float;
typedef unsigned long long u64;

static constexpr int TT  = 2048;   // time steps
static constexpr int NB  = 16;     // batch
static constexpr int SS  = 512;    // state dim
static constexpr int NWG = 4;      // cooperative scan workgroups (128 cols each)

__device__ __forceinline__ u64 tagpack(float f, unsigned tag) {
    return ((u64)tag << 32) | (u64)__float_as_uint(f);
}
__device__ __forceinline__ float tagval(u64 v) {
    return __uint_as_float((unsigned)(v & 0xFFFFFFFFu));
}

// -------------------- transpose + fp32->f16 (512x512): out[c][r] = in[r][c] --------------------
__global__ __launch_bounds__(256) void tcvt_kernel(const float* __restrict__ in,
                                                   _Float16* __restrict__ out) {
    __shared__ float tile[32][33];
    int bid = blockIdx.x;
    int rb = (bid >> 4) * 32, cb = (bid & 15) * 32;
    int tx = threadIdx.x & 31, ty = threadIdx.x >> 5;
    for (int rr = ty; rr < 32; rr += 8)
        tile[rr][tx] = in[(size_t)(rb + rr) * SS + cb + tx];
    __syncthreads();
    for (int rr = ty; rr < 32; rr += 8)
        out[(size_t)(cb + rr) * SS + rb + tx] = (_Float16)tile[tx][rr];
}

// -------------------- W = C0 @ B1 (512x512x512 fp32) --------------------
__global__ __launch_bounds__(256) void wmm_kernel(const float* __restrict__ C0,
                                                  const float* __restrict__ B1,
                                                  float* __restrict__ W) {
    int k = blockIdx.x;
    int tid = threadIdx.x;
    const float* crow = C0 + (size_t)k * SS;
    float s0 = 0.f, s1 = 0.f;
    for (int m = 0; m < SS; ++m) {
        float cv = crow[m];
        s0 += cv * B1[(size_t)m * SS + tid];
        s1 += cv * B1[(size_t)m * SS + tid + 256];
    }
    W[(size_t)k * SS + tid] = s0;
    W[(size_t)k * SS + tid + 256] = s1;
}

// -------------------- zero tagged stats mailbox (every launch: graph replay safe) ---------------
__global__ __launch_bounds__(256) void zinit_kernel(u64* __restrict__ p, int n) {
    int i = blockIdx.x * blockDim.x + threadIdx.x;
    if (i < n) p[i] = 0ull;
}

// -------------------- big GEMM: M=32768(b*2048+t), N=512, K=512 --------------------
// BT: f16 [n][k]. ALAY 0: A fp32 [m][k]; ALAY 1: A f16 [m][k].
// MODE 0: f16 out[m][n]; MODE 1: fp32 out[m][n]; MODE 2: f16 out in scan layout [t][b][n].
template <int ALAY, int MODE>
__global__ __launch_bounds__(256) void gemm_kernel(const void* __restrict__ Aptr,
                                                   const _Float16* __restrict__ BT,
                                                   void* __restrict__ Outp) {
    int lane = threadIdx.x & 63;
    int wv   = threadIdx.x >> 6;
    int wid  = blockIdx.x * 4 + wv;
    int mt   = wid >> 3;
    int nb   = (wid & 7) * 64;
    int mbase = mt * 16;
    int lo = lane & 15, q = lane >> 4;

    f32x4 acc[4] = {{0,0,0,0},{0,0,0,0},{0,0,0,0},{0,0,0,0}};

    const float*    Af = (const float*)Aptr;
    const _Float16* Ah = (const _Float16*)Aptr;
    size_t arow = (size_t)(mbase + lo) * SS;

    #pragma unroll 2
    for (int kk = 0; kk < 16; ++kk) {
        int koff = kk * 32 + q * 8;
        half8 af;
        if (ALAY == 0) {
            const float* ar = Af + arow + koff;
            f32x4 a0 = *(const f32x4*)ar;
            f32x4 a1 = *(const f32x4*)(ar + 4);
            #pragma unroll
            for (int j = 0; j < 4; ++j) { af[j] = (_Float16)a0[j]; af[4 + j] = (_Float16)a1[j]; }
        } else {
            af = *(const half8*)(Ah + arow + koff);
        }
        #pragma unroll
        for (int j = 0; j < 4; ++j) {
            int n = nb + j * 16 + lo;
            half8 bf = *(const half8*)(BT + (size_t)n * SS + koff);
            acc[j] = __builtin_amdgcn_mfma_f32_16x16x32_f16(af, bf, acc[j], 0, 0, 0);
        }
    }

    #pragma unroll
    for (int j = 0; j < 4; ++j) {
        #pragma unroll
        for (int i = 0; i < 4; ++i) {
            int m = mbase + q * 4 + i;
            int n = nb + j * 16 + lo;
            if (MODE == 0) {
                ((_Float16*)Outp)[(size_t)m * SS + n] = (_Float16)acc[j][i];
            } else if (MODE == 1) {
                ((float*)Outp)[(size_t)m * SS + n] = acc[j][i];
            } else {
                int t2 = m & (TT - 1);
                int b2 = m >> 11;                 // T = 2048 = 2^11
                ((_Float16*)Outp)[((size_t)t2 * NB + b2) * SS + n] = (_Float16)acc[j][i];
            }
        }
    }
}

// -------------------- cooperative liquid scan: 4 WGs, tagged-stats sync ------------------------
// IDENTICAL protocol to the round-8 passing kernel (scan9). One change:
// __launch_bounds__(512, 2) == exactly 1 WG/CU -> 256-VGPR cap, so the register allocator can
// keep the 128 VGPRs of A/K weight slices RESIDENT across the time loop instead of re-streaming
// 256 KB/step from L2 inside the MFMA loop (round-8 counters: VGPR_Count=112 < 128 weight VGPRs
// proved the "preload" was being re-loaded every step).
__global__ __launch_bounds__(512, 2) void scan10_kernel(
        const _Float16* __restrict__ U,     // [T][NB][SS]
        const float* __restrict__ Amat,     // [SS][SS] fp32 (k-major rows)
        const float* __restrict__ Kmat,     // [SS][SS]
        const float* __restrict__ ab,
        const float* __restrict__ gn,
        const float* __restrict__ bt,
        _Float16* __restrict__ hs,          // [NB][T][SS] history out
        u64*      __restrict__ zmail,       // [2][NWG][1024] u64 == [2][NWG][16][128] f32
        u64*      __restrict__ smail,       // [2][16][NWG][2] u64 tagged (S1,S2)
        unsigned  tagbase)
{
    const int wg   = blockIdx.x;
    const int tid  = threadIdx.x;
    const int wv   = tid >> 6;      // 0..7
    const int lane = tid & 63;
    const int q    = lane >> 4;
    const int r    = lane & 15;

    __shared__ _Float16 H16[16][520];            // f16 H for MFMA A-frags
    __shared__ float    HF[16][516];             // fp32 master accumulator of H
    alignas(16) __shared__ float ZW32[16][128];  // own z slice staging (fp32)
    __shared__ float    STAT[8][16][2];          // per-wave partial (S1,S2) per batch
    __shared__ float    GG[512];
    __shared__ float    BB[512];

    const int ub = tid & 15;            // h-update batch
    const int ug = tid >> 4;            // 0..31
    const int uc = ug * 16;             // h-update col start
    const int ow = ug >> 3;             // owning WG of this col slice (0..3)
    const int wc = (ug & 7) * 16;       // col offset within owner WG's 128-col slice

    for (int e = tid; e < 16 * 520; e += 512) (&H16[0][0])[e] = (_Float16)0.f;
    for (int e = tid; e < 16 * 516; e += 512) (&HF[0][0])[e] = 0.f;
    GG[tid] = gn[tid];
    BB[tid] = bt[tid];

    const int ccol = wg * 128 + wv * 16 + r;

    // one-time weight preload into registers (f16): 128 VGPR/lane, now actually resident
    half8 wA[16], wK[16];
    for (int ks = 0; ks < 16; ++ks) {
        half8 a, k;
        #pragma unroll
        for (int jj = 0; jj < 8; ++jj) {
            int kk = ks * 32 + q * 8 + jj;
            a[jj] = (_Float16)Amat[(size_t)kk * SS + ccol];
            k[jj] = (_Float16)Kmat[(size_t)kk * SS + ccol];
        }
        wA[ks] = a; wK[ks] = k;
    }
    const float abreg = ab[ccol];
    float uprev[4] = {0.f, 0.f, 0.f, 0.f};
    float ucur[4];
    #pragma unroll
    for (int i = 0; i < 4; ++i)
        ucur[i] = (float)U[(size_t)(q * 4 + i) * SS + ccol];   // t = 0
    __syncthreads();

    for (int t = 0; t < TT; ++t) {
        const int par = t & 1;
        const unsigned want = tagbase + (unsigned)t + 1u;

        // ---- MFMA phase: 16 batches x this wave's 16 cols ----
        f32x4 zA = {0.f, 0.f, 0.f, 0.f}, zK = {0.f, 0.f, 0.f, 0.f};
        #pragma unroll
        for (int ks = 0; ks < 16; ++ks) {
            half8 hf = *(const half8*)(&H16[r][ks * 32 + q * 8]);
            zA = __builtin_amdgcn_mfma_f32_16x16x32_f16(hf, wA[ks], zA, 0, 0, 0);
            zK = __builtin_amdgcn_mfma_f32_16x16x32_f16(hf, wK[ks], zK, 0, 0, 0);
        }
        float z[4];
        #pragma unroll
        for (int i = 0; i < 4; ++i) {
            z[i] = zA[i] + ucur[i] + abreg + zK[i] * uprev[i];
            uprev[i] = ucur[i];
            ZW32[q * 4 + i][wv * 16 + r] = z[i];
        }
        // issue next-step U prefetch NOW (latency overlaps reduce + publish)
        {
            const int tn = (t + 1) & (TT - 1);
            #pragma unroll
            for (int i = 0; i < 4; ++i)
                ucur[i] = (float)U[((size_t)tn * NB + (q * 4 + i)) * SS + ccol];
        }
        // per-wave LN partial over its 16 cols (reduce over r bits; q*4+i = batch)
        float s1[4], s2[4];
        #pragma unroll
        for (int i = 0; i < 4; ++i) { s1[i] = z[i]; s2[i] = z[i] * z[i]; }
        #pragma unroll
        for (int off = 1; off < 16; off <<= 1) {
            #pragma unroll
            for (int i = 0; i < 4; ++i) {
                s1[i] += __shfl_xor(s1[i], off, 64);
                s2[i] += __shfl_xor(s2[i], off, 64);
            }
        }
        if (r == 0) {
            #pragma unroll
            for (int i = 0; i < 4; ++i) {
                STAT[wv][q * 4 + i][0] = s1[i];
                STAT[wv][q * 4 + i][1] = s2[i];
            }
        }
        __syncthreads();                                   // B1: ZW32/STAT ready

        // publish z slice: 512 threads x two contiguous 8B agent-scope atomic stores
        {
            const u64* zs = (const u64*)ZW32;
            u64* zd = &zmail[((size_t)par * NWG + wg) * 1024];
            __hip_atomic_store(zd + tid,       zs[tid],       __ATOMIC_RELAXED, __HIP_MEMORY_SCOPE_AGENT);
            __hip_atomic_store(zd + tid + 512, zs[tid + 512], __ATOMIC_RELAXED, __HIP_MEMORY_SCOPE_AGENT);
        }
        __builtin_amdgcn_s_waitcnt(0);
        __syncthreads();                                   // B2: all z at coherence point

        // wave0: publish TAGGED stats, then spin on 3 peers x 32 tagged words
        if (wv == 0) {
            if (lane < 16) {
                float S1 = 0.f, S2 = 0.f;
                #pragma unroll
                for (int v = 0; v < 8; ++v) { S1 += STAT[v][lane][0]; S2 += STAT[v][lane][1]; }
                u64* sd = &smail[(((size_t)par * 16 + lane) * NWG + wg) * 2];
                __hip_atomic_store(sd + 0, tagpack(S1, want), __ATOMIC_RELAXED, __HIP_MEMORY_SCOPE_AGENT);
                __hip_atomic_store(sd + 1, tagpack(S2, want), __ATOMIC_RELAXED, __HIP_MEMORY_SCOPE_AGENT);
            }
            // flattened peer-word ids: f in 0..95; lane handles f=lane and (lane<32) f=lane+64
            {
                const int f0 = lane;
                const int p0 = (f0 >> 5) + 1, w0 = f0 & 31;
                const u64* a0 = &smail[(((size_t)par * 16 + (w0 >> 1)) * NWG + ((wg + p0) & (NWG - 1))) * 2 + (w0 & 1)];
                const int f1 = 64 + lane;
                const int p1 = (f1 >> 5) + 1, w1 = f1 & 31;
                const u64* a1 = &smail[(((size_t)par * 16 + (w1 >> 1)) * NWG + ((wg + p1) & (NWG - 1))) * 2 + (w1 & 1)];
                const bool two = (lane < 32);
                for (;;) {
                    unsigned t0 = (unsigned)(__hip_atomic_load(a0, __ATOMIC_RELAXED, __HIP_MEMORY_SCOPE_AGENT) >> 32);
                    unsigned t1 = two ? (unsigned)(__hip_atomic_load(a1, __ATOMIC_RELAXED, __HIP_MEMORY_SCOPE_AGENT) >> 32)
                                      : want;
                    if (t0 == want && t1 == want) break;
                }
            }
        }
        __syncthreads();                                   // B3: all WGs' z+stats readable

        // gather: 8 tagged stats (own batch, all 4 WGs ascending) + 16 z values
        u64 sv[8];
        #pragma unroll
        for (int w2 = 0; w2 < NWG; ++w2) {
            const u64* sp = &smail[(((size_t)par * 16 + ub) * NWG + w2) * 2];
            sv[w2 * 2]     = __hip_atomic_load(sp + 0, __ATOMIC_RELAXED, __HIP_MEMORY_SCOPE_AGENT);
            sv[w2 * 2 + 1] = __hip_atomic_load(sp + 1, __ATOMIC_RELAXED, __HIP_MEMORY_SCOPE_AGENT);
        }
        float zz[16];
        if (ow == wg) {
            #pragma unroll
            for (int i = 0; i < 16; ++i) zz[i] = ZW32[ub][wc + i];
        } else {
            union { u64 u[8]; float f[16]; } zu;
            const u64* zp = &zmail[((size_t)par * NWG + ow) * 1024 + (size_t)ub * 64 + (wc >> 1)];
            #pragma unroll
            for (int i = 0; i < 8; ++i)
                zu.u[i] = __hip_atomic_load(zp + i, __ATOMIC_RELAXED, __HIP_MEMORY_SCOPE_AGENT);
            #pragma unroll
            for (int i = 0; i < 16; ++i) zz[i] = zu.f[i];
        }
        // fixed ascending WG order -> bit-identical mu/rs in every WG
        float S1 = 0.f, S2 = 0.f;
        #pragma unroll
        for (int w2 = 0; w2 < NWG; ++w2) { S1 += tagval(sv[w2 * 2]); S2 += tagval(sv[w2 * 2 + 1]); }
        const float mu  = S1 * (1.0f / SS);
        const float var = S2 * (1.0f / SS) - mu * mu;
        const float rs  = rsqrtf(var + 1e-5f);

        // replicated LN + exact GELU + h update (16 elems/thread), identical in all WGs
        half8 hh0, hh1;
        #pragma unroll
        for (int i4 = 0; i4 < 4; ++i4) {
            f32x4 gq = *(const f32x4*)&GG[uc + i4 * 4];
            f32x4 bq = *(const f32x4*)&BB[uc + i4 * 4];
            f32x4 hq = *(const f32x4*)&HF[ub][uc + i4 * 4];
            #pragma unroll
            for (int jj = 0; jj < 4; ++jj) {
                const int e = i4 * 4 + jj;
                float zn = (zz[e] - mu) * rs * gq[jj] + bq[jj];
                float ge = 0.5f * zn * (1.0f + erff(zn * 0.70710678118654752f));
                float hv = hq[jj] + ge;
                hq[jj] = hv;
                if (e < 8) hh0[e] = (_Float16)hv; else hh1[e - 8] = (_Float16)hv;
            }
            *(f32x4*)&HF[ub][uc + i4 * 4] = hq;
        }
        *(half8*)(&H16[ub][uc])     = hh0;
        *(half8*)(&H16[ub][uc + 8]) = hh1;
        if (ow == wg) {   // slice owner writes history
            _Float16* hd = hs + ((size_t)ub * TT + t) * SS + uc;
            *(half8*)(hd)     = hh0;
            *(half8*)(hd + 8) = hh1;
        }
        __syncthreads();                                   // B5: H16/ZW32/STAT free for next step
    }
}

// -------------------- host launch --------------------
extern "C" void kernel_launch(void* const* d_in, const int* in_sizes, int n_in,
                              void* d_out, int out_size, void* d_ws, size_t ws_size,
                              hipStream_t stream) {
    const float* x   = (const float*)d_in[0];
    const float* A0  = (const float*)d_in[1];
    const float* B0  = (const float*)d_in[2];
    const float* C0  = (const float*)d_in[3];
    const float* K0  = (const float*)d_in[4];
    const float* ab0 = (const float*)d_in[5];
    const float* g0  = (const float*)d_in[6];
    const float* bt0 = (const float*)d_in[7];
    const float* A1  = (const float*)d_in[8];
    const float* B1  = (const float*)d_in[9];
    const float* C1  = (const float*)d_in[10];
    const float* K1  = (const float*)d_in[11];
    const float* ab1 = (const float*)d_in[12];
    const float* g1  = (const float*)d_in[13];
    const float* bt1 = (const float*)d_in[14];

    char* ws = (char*)d_ws;
    size_t off = 0;
    auto alloc = [&](size_t bytes) { size_t o = off; off = (off + bytes + 255) & ~(size_t)255; return o; };

    const size_t BUF_BYTES = (size_t)NB * TT * SS * 2;   // 33.5 MB f16
    const size_t WP_BYTES  = (size_t)SS * SS * 2;        // 512 KB f16

    _Float16* U0  = (_Float16*)(ws + alloc(BUF_BYTES));  // [t][b][c]
    _Float16* U1  = (_Float16*)(ws + alloc(BUF_BYTES));  // [t][b][c]
    _Float16* hs0 = (_Float16*)(ws + alloc(BUF_BYTES));  // [b][t][c]
    _Float16* hs1 = (_Float16*)(ws + alloc(BUF_BYTES));  // [b][t][c]
    _Float16* B0T = (_Float16*)(ws + alloc(WP_BYTES));
    _Float16* WT  = (_Float16*)(ws + alloc(WP_BYTES));
    _Float16* C1T = (_Float16*)(ws + alloc(WP_BYTES));
    float*    Wf  = (float*)(ws + alloc((size_t)SS * SS * 4));
    u64*      zmail = (u64*)(ws + alloc((size_t)2 * NWG * 1024 * 8));  // 64 KB
    u64*      smail = (u64*)(ws + alloc((size_t)2 * 16 * NWG * 2 * 8)); // 2 KB tagged stats

    const int SN = 2 * 16 * NWG * 2;   // 256 u64

    // zero tagged stats mailbox (stream-ordered; graph-replay safe)
    zinit_kernel<<<1, 256, 0, stream>>>(smail, SN);

    // weight preps
    tcvt_kernel<<<256, 256, 0, stream>>>(B0, B0T);
    tcvt_kernel<<<256, 256, 0, stream>>>(C1, C1T);
    wmm_kernel<<<512, 256, 0, stream>>>(C0, B1, Wf);     // W = C0 @ B1 (layer-fold)
    tcvt_kernel<<<256, 256, 0, stream>>>(Wf, WT);

    // U0 = x @ B0, scan layout [t][b][c]
    gemm_kernel<0, 2><<<4096, 256, 0, stream>>>((const void*)x, B0T, (void*)U0);

    // layer-0 cooperative scan (tags 1..TT)
    scan10_kernel<<<NWG, 512, 0, stream>>>(U0, A0, K0, ab0, g0, bt0, hs0, zmail, smail, 0u);

    // U1 = hs0 @ (C0@B1), scan layout
    gemm_kernel<1, 2><<<4096, 256, 0, stream>>>((const void*)hs0, WT, (void*)U1);

    // layer-1 cooperative scan (tags TT+1..2*TT)
    scan10_kernel<<<NWG, 512, 0, stream>>>(U1, A1, K1, ab1, g1, bt1, hs1, zmail, smail, (unsigned)TT);

    // out = hs1 @ C1 (fp32 [b][t][c])
    gemm_kernel<1, 1><<<4096, 256, 0, stream>>>((const void*)hs1, C1T, d_out);
}

// Round 10
// 27706.729 us; speedup vs baseline: 1.0476x; 1.0476x over previous
//
#include <hip/hip_runtime.h>

using half8 = __attribute__((ext_vector_type(8))) _Float16;
using f32x4 = __attribute__((ext_vector_type(4))) float;
typedef unsigned long long u64;

static constexpr int TT  = 2048;   // time steps
static constexpr int NB  = 16;     // batch
static constexpr int SS  = 512;    // state dim
static constexpr int NWG = 4;      // cooperative scan workgroups (128 cols each)

__device__ __forceinline__ u64 tagpack(float f, unsigned tag) {
    return ((u64)tag << 32) | (u64)__float_as_uint(f);
}
__device__ __forceinline__ float tagval(u64 v) {
    return __uint_as_float((unsigned)(v & 0xFFFFFFFFu));
}

// -------------------- transpose + fp32->f16 (512x512): out[c][r] = in[r][c] --------------------
__global__ __launch_bounds__(256) void tcvt_kernel(const float* __restrict__ in,
                                                   _Float16* __restrict__ out) {
    __shared__ float tile[32][33];
    int bid = blockIdx.x;
    int rb = (bid >> 4) * 32, cb = (bid & 15) * 32;
    int tx = threadIdx.x & 31, ty = threadIdx.x >> 5;
    for (int rr = ty; rr < 32; rr += 8)
        tile[rr][tx] = in[(size_t)(rb + rr) * SS + cb + tx];
    __syncthreads();
    for (int rr = ty; rr < 32; rr += 8)
        out[(size_t)(cb + rr) * SS + rb + tx] = (_Float16)tile[tx][rr];
}

// -------------------- W = C0 @ B1 (512x512x512 fp32) --------------------
__global__ __launch_bounds__(256) void wmm_kernel(const float* __restrict__ C0,
                                                  const float* __restrict__ B1,
                                                  float* __restrict__ W) {
    int k = blockIdx.x;
    int tid = threadIdx.x;
    const float* crow = C0 + (size_t)k * SS;
    float s0 = 0.f, s1 = 0.f;
    for (int m = 0; m < SS; ++m) {
        float cv = crow[m];
        s0 += cv * B1[(size_t)m * SS + tid];
        s1 += cv * B1[(size_t)m * SS + tid + 256];
    }
    W[(size_t)k * SS + tid] = s0;
    W[(size_t)k * SS + tid + 256] = s1;
}

// -------------------- zero tagged stats mailbox (every launch: graph replay safe) ---------------
__global__ __launch_bounds__(256) void zinit_kernel(u64* __restrict__ p, int n) {
    int i = blockIdx.x * blockDim.x + threadIdx.x;
    if (i < n) p[i] = 0ull;
}

// -------------------- big GEMM: M=32768(b*2048+t), N=512, K=512 --------------------
// BT: f16 [n][k]. ALAY 0: A fp32 [m][k]; ALAY 1: A f16 [m][k].
// MODE 0: f16 out[m][n]; MODE 1: fp32 out[m][n]; MODE 2: f16 out in scan layout [t][b][n].
template <int ALAY, int MODE>
__global__ __launch_bounds__(256) void gemm_kernel(const void* __restrict__ Aptr,
                                                   const _Float16* __restrict__ BT,
                                                   void* __restrict__ Outp) {
    int lane = threadIdx.x & 63;
    int wv   = threadIdx.x >> 6;
    int wid  = blockIdx.x * 4 + wv;
    int mt   = wid >> 3;
    int nb   = (wid & 7) * 64;
    int mbase = mt * 16;
    int lo = lane & 15, q = lane >> 4;

    f32x4 acc[4] = {{0,0,0,0},{0,0,0,0},{0,0,0,0},{0,0,0,0}};

    const float*    Af = (const float*)Aptr;
    const _Float16* Ah = (const _Float16*)Aptr;
    size_t arow = (size_t)(mbase + lo) * SS;

    #pragma unroll 2
    for (int kk = 0; kk < 16; ++kk) {
        int koff = kk * 32 + q * 8;
        half8 af;
        if (ALAY == 0) {
            const float* ar = Af + arow + koff;
            f32x4 a0 = *(const f32x4*)ar;
            f32x4 a1 = *(const f32x4*)(ar + 4);
            #pragma unroll
            for (int j = 0; j < 4; ++j) { af[j] = (_Float16)a0[j]; af[4 + j] = (_Float16)a1[j]; }
        } else {
            af = *(const half8*)(Ah + arow + koff);
        }
        #pragma unroll
        for (int j = 0; j < 4; ++j) {
            int n = nb + j * 16 + lo;
            half8 bf = *(const half8*)(BT + (size_t)n * SS + koff);
            acc[j] = __builtin_amdgcn_mfma_f32_16x16x32_f16(af, bf, acc[j], 0, 0, 0);
        }
    }

    #pragma unroll
    for (int j = 0; j < 4; ++j) {
        #pragma unroll
        for (int i = 0; i < 4; ++i) {
            int m = mbase + q * 4 + i;
            int n = nb + j * 16 + lo;
            if (MODE == 0) {
                ((_Float16*)Outp)[(size_t)m * SS + n] = (_Float16)acc[j][i];
            } else if (MODE == 1) {
                ((float*)Outp)[(size_t)m * SS + n] = acc[j][i];
            } else {
                int t2 = m & (TT - 1);
                int b2 = m >> 11;                 // T = 2048 = 2^11
                ((_Float16*)Outp)[((size_t)t2 * NB + b2) * SS + n] = (_Float16)acc[j][i];
            }
        }
    }
}

// -------------------- cooperative liquid scan: 4 WGs, tagged-stats sync ------------------------
// IDENTICAL protocol to the round-8/9 passing kernel. One change: the weight-preload loop is
// FULLY UNROLLED (#pragma unroll) so wA/wK are written with compile-time-constant indices ->
// SROA promotes them to registers. Round-9 counters proved the arrays were in SCRATCH
// (VGPR_Count=112 < the 128 weight VGPRs despite a 256 cap): every step re-read 512B/lane of
// weights from scratch inside the MFMA phase (~2us/step). launch_bounds(512,2) keeps the
// 256-VGPR cap so the now-promoted arrays fit (1 WG/CU; we only launch 4 WGs anyway).
__global__ __launch_bounds__(512, 2) void scan11_kernel(
        const _Float16* __restrict__ U,     // [T][NB][SS]
        const float* __restrict__ Amat,     // [SS][SS] fp32 (k-major rows)
        const float* __restrict__ Kmat,     // [SS][SS]
        const float* __restrict__ ab,
        const float* __restrict__ gn,
        const float* __restrict__ bt,
        _Float16* __restrict__ hs,          // [NB][T][SS] history out
        u64*      __restrict__ zmail,       // [2][NWG][1024] u64 == [2][NWG][16][128] f32
        u64*      __restrict__ smail,       // [2][16][NWG][2] u64 tagged (S1,S2)
        unsigned  tagbase)
{
    const int wg   = blockIdx.x;
    const int tid  = threadIdx.x;
    const int wv   = tid >> 6;      // 0..7
    const int lane = tid & 63;
    const int q    = lane >> 4;
    const int r    = lane & 15;

    __shared__ _Float16 H16[16][520];            // f16 H for MFMA A-frags
    __shared__ float    HF[16][516];             // fp32 master accumulator of H
    alignas(16) __shared__ float ZW32[16][128];  // own z slice staging (fp32)
    __shared__ float    STAT[8][16][2];          // per-wave partial (S1,S2) per batch
    __shared__ float    GG[512];
    __shared__ float    BB[512];

    const int ub = tid & 15;            // h-update batch
    const int ug = tid >> 4;            // 0..31
    const int uc = ug * 16;             // h-update col start
    const int ow = ug >> 3;             // owning WG of this col slice (0..3)
    const int wc = (ug & 7) * 16;       // col offset within owner WG's 128-col slice

    for (int e = tid; e < 16 * 520; e += 512) (&H16[0][0])[e] = (_Float16)0.f;
    for (int e = tid; e < 16 * 516; e += 512) (&HF[0][0])[e] = 0.f;
    GG[tid] = gn[tid];
    BB[tid] = bt[tid];

    const int ccol = wg * 128 + wv * 16 + r;

    // one-time weight preload into registers (f16): 128 VGPR/lane.
    // FULL UNROLL is mandatory: every wA[ks]/wK[ks] access must be a static index or the
    // arrays land in scratch and get re-read every timestep (round-9 lesson).
    half8 wA[16], wK[16];
    #pragma unroll
    for (int ks = 0; ks < 16; ++ks) {
        half8 a, k;
        #pragma unroll
        for (int jj = 0; jj < 8; ++jj) {
            int kk = ks * 32 + q * 8 + jj;
            a[jj] = (_Float16)Amat[(size_t)kk * SS + ccol];
            k[jj] = (_Float16)Kmat[(size_t)kk * SS + ccol];
        }
        wA[ks] = a; wK[ks] = k;
    }
    const float abreg = ab[ccol];
    float uprev[4] = {0.f, 0.f, 0.f, 0.f};
    float ucur[4];
    #pragma unroll
    for (int i = 0; i < 4; ++i)
        ucur[i] = (float)U[(size_t)(q * 4 + i) * SS + ccol];   // t = 0
    __syncthreads();

    for (int t = 0; t < TT; ++t) {
        const int par = t & 1;
        const unsigned want = tagbase + (unsigned)t + 1u;

        // ---- MFMA phase: 16 batches x this wave's 16 cols ----
        f32x4 zA = {0.f, 0.f, 0.f, 0.f}, zK = {0.f, 0.f, 0.f, 0.f};
        #pragma unroll
        for (int ks = 0; ks < 16; ++ks) {
            half8 hf = *(const half8*)(&H16[r][ks * 32 + q * 8]);
            zA = __builtin_amdgcn_mfma_f32_16x16x32_f16(hf, wA[ks], zA, 0, 0, 0);
            zK = __builtin_amdgcn_mfma_f32_16x16x32_f16(hf, wK[ks], zK, 0, 0, 0);
        }
        float z[4];
        #pragma unroll
        for (int i = 0; i < 4; ++i) {
            z[i] = zA[i] + ucur[i] + abreg + zK[i] * uprev[i];
            uprev[i] = ucur[i];
            ZW32[q * 4 + i][wv * 16 + r] = z[i];
        }
        // issue next-step U prefetch NOW (latency overlaps reduce + publish)
        {
            const int tn = (t + 1) & (TT - 1);
            #pragma unroll
            for (int i = 0; i < 4; ++i)
                ucur[i] = (float)U[((size_t)tn * NB + (q * 4 + i)) * SS + ccol];
        }
        // per-wave LN partial over its 16 cols (reduce over r bits; q*4+i = batch)
        float s1[4], s2[4];
        #pragma unroll
        for (int i = 0; i < 4; ++i) { s1[i] = z[i]; s2[i] = z[i] * z[i]; }
        #pragma unroll
        for (int off = 1; off < 16; off <<= 1) {
            #pragma unroll
            for (int i = 0; i < 4; ++i) {
                s1[i] += __shfl_xor(s1[i], off, 64);
                s2[i] += __shfl_xor(s2[i], off, 64);
            }
        }
        if (r == 0) {
            #pragma unroll
            for (int i = 0; i < 4; ++i) {
                STAT[wv][q * 4 + i][0] = s1[i];
                STAT[wv][q * 4 + i][1] = s2[i];
            }
        }
        __syncthreads();                                   // B1: ZW32/STAT ready

        // publish z slice: 512 threads x two contiguous 8B agent-scope atomic stores
        {
            const u64* zs = (const u64*)ZW32;
            u64* zd = &zmail[((size_t)par * NWG + wg) * 1024];
            __hip_atomic_store(zd + tid,       zs[tid],       __ATOMIC_RELAXED, __HIP_MEMORY_SCOPE_AGENT);
            __hip_atomic_store(zd + tid + 512, zs[tid + 512], __ATOMIC_RELAXED, __HIP_MEMORY_SCOPE_AGENT);
        }
        __builtin_amdgcn_s_waitcnt(0);
        __syncthreads();                                   // B2: all z at coherence point

        // wave0: publish TAGGED stats, then spin on 3 peers x 32 tagged words
        if (wv == 0) {
            if (lane < 16) {
                float S1 = 0.f, S2 = 0.f;
                #pragma unroll
                for (int v = 0; v < 8; ++v) { S1 += STAT[v][lane][0]; S2 += STAT[v][lane][1]; }
                u64* sd = &smail[(((size_t)par * 16 + lane) * NWG + wg) * 2];
                __hip_atomic_store(sd + 0, tagpack(S1, want), __ATOMIC_RELAXED, __HIP_MEMORY_SCOPE_AGENT);
                __hip_atomic_store(sd + 1, tagpack(S2, want), __ATOMIC_RELAXED, __HIP_MEMORY_SCOPE_AGENT);
            }
            // flattened peer-word ids: f in 0..95; lane handles f=lane and (lane<32) f=lane+64
            {
                const int f0 = lane;
                const int p0 = (f0 >> 5) + 1, w0 = f0 & 31;
                const u64* a0 = &smail[(((size_t)par * 16 + (w0 >> 1)) * NWG + ((wg + p0) & (NWG - 1))) * 2 + (w0 & 1)];
                const int f1 = 64 + lane;
                const int p1 = (f1 >> 5) + 1, w1 = f1 & 31;
                const u64* a1 = &smail[(((size_t)par * 16 + (w1 >> 1)) * NWG + ((wg + p1) & (NWG - 1))) * 2 + (w1 & 1)];
                const bool two = (lane < 32);
                for (;;) {
                    unsigned t0 = (unsigned)(__hip_atomic_load(a0, __ATOMIC_RELAXED, __HIP_MEMORY_SCOPE_AGENT) >> 32);
                    unsigned t1 = two ? (unsigned)(__hip_atomic_load(a1, __ATOMIC_RELAXED, __HIP_MEMORY_SCOPE_AGENT) >> 32)
                                      : want;
                    if (t0 == want && t1 == want) break;
                }
            }
        }
        __syncthreads();                                   // B3: all WGs' z+stats readable

        // gather: 8 tagged stats (own batch, all 4 WGs ascending) + 16 z values
        u64 sv[8];
        #pragma unroll
        for (int w2 = 0; w2 < NWG; ++w2) {
            const u64* sp = &smail[(((size_t)par * 16 + ub) * NWG + w2) * 2];
            sv[w2 * 2]     = __hip_atomic_load(sp + 0, __ATOMIC_RELAXED, __HIP_MEMORY_SCOPE_AGENT);
            sv[w2 * 2 + 1] = __hip_atomic_load(sp + 1, __ATOMIC_RELAXED, __HIP_MEMORY_SCOPE_AGENT);
        }
        float zz[16];
        if (ow == wg) {
            #pragma unroll
            for (int i = 0; i < 16; ++i) zz[i] = ZW32[ub][wc + i];
        } else {
            union { u64 u[8]; float f[16]; } zu;
            const u64* zp = &zmail[((size_t)par * NWG + ow) * 1024 + (size_t)ub * 64 + (wc >> 1)];
            #pragma unroll
            for (int i = 0; i < 8; ++i)
                zu.u[i] = __hip_atomic_load(zp + i, __ATOMIC_RELAXED, __HIP_MEMORY_SCOPE_AGENT);
            #pragma unroll
            for (int i = 0; i < 16; ++i) zz[i] = zu.f[i];
        }
        // fixed ascending WG order -> bit-identical mu/rs in every WG
        float S1 = 0.f, S2 = 0.f;
        #pragma unroll
        for (int w2 = 0; w2 < NWG; ++w2) { S1 += tagval(sv[w2 * 2]); S2 += tagval(sv[w2 * 2 + 1]); }
        const float mu  = S1 * (1.0f / SS);
        const float var = S2 * (1.0f / SS) - mu * mu;
        const float rs  = rsqrtf(var + 1e-5f);

        // replicated LN + exact GELU + h update (16 elems/thread), identical in all WGs
        half8 hh0, hh1;
        #pragma unroll
        for (int i4 = 0; i4 < 4; ++i4) {
            f32x4 gq = *(const f32x4*)&GG[uc + i4 * 4];
            f32x4 bq = *(const f32x4*)&BB[uc + i4 * 4];
            f32x4 hq = *(const f32x4*)&HF[ub][uc + i4 * 4];
            #pragma unroll
            for (int jj = 0; jj < 4; ++jj) {
                const int e = i4 * 4 + jj;
                float zn = (zz[e] - mu) * rs * gq[jj] + bq[jj];
                float ge = 0.5f * zn * (1.0f + erff(zn * 0.70710678118654752f));
                float hv = hq[jj] + ge;
                hq[jj] = hv;
                if (e < 8) hh0[e] = (_Float16)hv; else hh1[e - 8] = (_Float16)hv;
            }
            *(f32x4*)&HF[ub][uc + i4 * 4] = hq;
        }
        *(half8*)(&H16[ub][uc])     = hh0;
        *(half8*)(&H16[ub][uc + 8]) = hh1;
        if (ow == wg) {   // slice owner writes history
            _Float16* hd = hs + ((size_t)ub * TT + t) * SS + uc;
            *(half8*)(hd)     = hh0;
            *(half8*)(hd + 8) = hh1;
        }
        __syncthreads();                                   // B5: H16/ZW32/STAT free for next step
    }
}

// -------------------- host launch --------------------
extern "C" void kernel_launch(void* const* d_in, const int* in_sizes, int n_in,
                              void* d_out, int out_size, void* d_ws, size_t ws_size,
                              hipStream_t stream) {
    const float* x   = (const float*)d_in[0];
    const float* A0  = (const float*)d_in[1];
    const float* B0  = (const float*)d_in[2];
    const float* C0  = (const float*)d_in[3];
    const float* K0  = (const float*)d_in[4];
    const float* ab0 = (const float*)d_in[5];
    const float* g0  = (const float*)d_in[6];
    const float* bt0 = (const float*)d_in[7];
    const float* A1  = (const float*)d_in[8];
    const float* B1  = (const float*)d_in[9];
    const float* C1  = (const float*)d_in[10];
    const float* K1  = (const float*)d_in[11];
    const float* ab1 = (const float*)d_in[12];
    const float* g1  = (const float*)d_in[13];
    const float* bt1 = (const float*)d_in[14];

    char* ws = (char*)d_ws;
    size_t off = 0;
    auto alloc = [&](size_t bytes) { size_t o = off; off = (off + bytes + 255) & ~(size_t)255; return o; };

    const size_t BUF_BYTES = (size_t)NB * TT * SS * 2;   // 33.5 MB f16
    const size_t WP_BYTES  = (size_t)SS * SS * 2;        // 512 KB f16

    _Float16* U0  = (_Float16*)(ws + alloc(BUF_BYTES));  // [t][b][c]
    _Float16* U1  = (_Float16*)(ws + alloc(BUF_BYTES));  // [t][b][c]
    _Float16* hs0 = (_Float16*)(ws + alloc(BUF_BYTES));  // [b][t][c]
    _Float16* hs1 = (_Float16*)(ws + alloc(BUF_BYTES));  // [b][t][c]
    _Float16* B0T = (_Float16*)(ws + alloc(WP_BYTES));
    _Float16* WT  = (_Float16*)(ws + alloc(WP_BYTES));
    _Float16* C1T = (_Float16*)(ws + alloc(WP_BYTES));
    float*    Wf  = (float*)(ws + alloc((size_t)SS * SS * 4));
    u64*      zmail = (u64*)(ws + alloc((size_t)2 * NWG * 1024 * 8));  // 64 KB
    u64*      smail = (u64*)(ws + alloc((size_t)2 * 16 * NWG * 2 * 8)); // 2 KB tagged stats

    const int SN = 2 * 16 * NWG * 2;   // 256 u64

    // zero tagged stats mailbox (stream-ordered; graph-replay safe)
    zinit_kernel<<<1, 256, 0, stream>>>(smail, SN);

    // weight preps
    tcvt_kernel<<<256, 256, 0, stream>>>(B0, B0T);
    tcvt_kernel<<<256, 256, 0, stream>>>(C1, C1T);
    wmm_kernel<<<512, 256, 0, stream>>>(C0, B1, Wf);     // W = C0 @ B1 (layer-fold)
    tcvt_kernel<<<256, 256, 0, stream>>>(Wf, WT);

    // U0 = x @ B0, scan layout [t][b][c]
    gemm_kernel<0, 2><<<4096, 256, 0, stream>>>((const void*)x, B0T, (void*)U0);

    // layer-0 cooperative scan (tags 1..TT)
    scan11_kernel<<<NWG, 512, 0, stream>>>(U0, A0, K0, ab0, g0, bt0, hs0, zmail, smail, 0u);

    // U1 = hs0 @ (C0@B1), scan layout
    gemm_kernel<1, 2><<<4096, 256, 0, stream>>>((const void*)hs0, WT, (void*)U1);

    // layer-1 cooperative scan (tags TT+1..2*TT)
    scan11_kernel<<<NWG, 512, 0, stream>>>(U1, A1, K1, ab1, g1, bt1, hs1, zmail, smail, (unsigned)TT);

    // out = hs1 @ C1 (fp32 [b][t][c])
    gemm_kernel<1, 1><<<4096, 256, 0, stream>>>((const void*)hs1, C1T, d_out);
}